// Round 5
// baseline (176.247 us; speedup 1.0000x reference)
//
#include <hip/hip_runtime.h>

// out[b,o] = (rowsum(x)[b] + rowsum(w)[o]) * bias[o]
// B=8192, IN=2048, OUT=2048, all float32.
//
// ONE regular kernel, 512 blocks x 256 threads, co-resident by capacity
// (__launch_bounds__(256,2) guarantees >=2 blocks/CU -> 512 slots on 256 CUs).
// Per wave: reduce 1 w-row -> publish wsb + arrive (device-scope), then reduce
// 4 x-rows into registers (hides the producer window), spin until all 2048
// w-rows published (expected ~0 iterations), acquire-fence, stream out rows.

#define B_DIM 8192
#define IN_DIM 2048
#define OUT_DIM 2048
#define NBLK 512
#define WROWS_TOTAL 2048u

typedef float f32x4 __attribute__((ext_vector_type(4)));

__device__ __forceinline__ float butterfly_reduce(float s) {
    #pragma unroll
    for (int off = 32; off; off >>= 1)
        s += __shfl_xor(s, off, 64);
    return s;   // result in all 64 lanes
}

__device__ __forceinline__ float row_reduce(const f32x4* __restrict__ row4, int lane) {
    f32x4 v[8];
    #pragma unroll
    for (int k = 0; k < 8; ++k)
        v[k] = row4[lane + (k << 6)];
    float s = 0.f;
    #pragma unroll
    for (int k = 0; k < 8; ++k)
        s += (v[k].x + v[k].y) + (v[k].z + v[k].w);
    return butterfly_reduce(s);
}

__global__ __launch_bounds__(256, 2) void fused_all(const float* __restrict__ x,
                                                    const float* __restrict__ w,
                                                    const float* __restrict__ bias,
                                                    float* __restrict__ out,
                                                    float* __restrict__ wsb,
                                                    unsigned int* __restrict__ cnt) {
    const int tid  = threadIdx.x;
    const int wave = tid >> 6;
    const int lane = tid & 63;
    const int blk  = blockIdx.x;               // 0 .. 511

    // ---- produce: one w-row per wave ----
    const int wrow = (blk << 2) + wave;        // 0 .. 2047
    float ws_ = row_reduce(reinterpret_cast<const f32x4*>(w + (size_t)wrow * IN_DIM), lane);
    if (lane == 0) {
        wsb[wrow] = ws_ * bias[wrow];
        __threadfence();                       // release: wsb visible device-wide
        atomicAdd(cnt, 1u);                    // device-scope arrive
    }

    // ---- reduce 4 x-rows per wave (overlaps all producers) ----
    const int xbase = blk << 4;                // 16 x-rows per block
    float xs[4];
    #pragma unroll
    for (int r = 0; r < 4; ++r) {
        const int xrow = xbase + (r << 2) + wave;
        xs[r] = row_reduce(reinterpret_cast<const f32x4*>(x + (size_t)xrow * IN_DIM), lane);
    }

    // ---- wait until all 2048 w-rows published (expected ~0 spins) ----
    if (lane == 0) {
        while (__hip_atomic_load(cnt, __ATOMIC_ACQUIRE, __HIP_MEMORY_SCOPE_AGENT) < WROWS_TOTAL)
            __builtin_amdgcn_s_sleep(8);
    }   // wave reconverges here: all 64 lanes have waited
    __threadfence();                           // acquire: fresh wsb reads

    // ---- write 4 out rows per wave ----
    const f32x4* bias4 = reinterpret_cast<const f32x4*>(bias);
    const f32x4* wsb4  = reinterpret_cast<const f32x4*>(wsb);
    #pragma unroll
    for (int r = 0; r < 4; ++r) {
        const int xrow = xbase + (r << 2) + wave;
        f32x4* orow = reinterpret_cast<f32x4*>(out) + (size_t)xrow * (OUT_DIM / 4);
        const float xsr = xs[r];
        #pragma unroll
        for (int k = 0; k < 8; ++k) {
            const int i = lane + (k << 6);
            const f32x4 bi = bias4[i];         // L1/L2-resident broadcast
            const f32x4 wv = wsb4[i];
            f32x4 o;
            o.x = fmaf(xsr, bi.x, wv.x);
            o.y = fmaf(xsr, bi.y, wv.y);
            o.z = fmaf(xsr, bi.z, wv.z);
            o.w = fmaf(xsr, bi.w, wv.w);
            orow[i] = o;
        }
    }
}

extern "C" void kernel_launch(void* const* d_in, const int* in_sizes, int n_in,
                              void* d_out, int out_size, void* d_ws, size_t ws_size,
                              hipStream_t stream) {
    const float* x    = (const float*)d_in[0];   // [8192, 2048]
    const float* w    = (const float*)d_in[1];   // [2048, 2048]
    const float* bias = (const float*)d_in[2];   // [2048]
    float* out = (float*)d_out;                  // [8192, 2048]

    unsigned int* cnt = (unsigned int*)d_ws;             // arrive counter
    float* wsb = (float*)((char*)d_ws + 256);            // 2048 floats

    hipMemsetAsync(d_ws, 0, 4, stream);                  // zero counter every call

    fused_all<<<NBLK, 256, 0, stream>>>(x, w, bias, out, wsb, cnt);
}

// Round 6
// 30.512 us; speedup vs baseline: 5.7762x; 5.7762x over previous
//
#include <hip/hip_runtime.h>

// out[b,o] = (rowsum(x)[b] + rowsum(w)[o]) * bias[o]
// B=8192, IN=2048, OUT=2048, all float32.
//
// Kernel A: wsb[o] = rowsum(w)[o]*bias[o]. Wave-per-row, no LDS/sync.
// Kernel B: wave-per-row over x, 4 rows/wave, depth-2 software pipeline:
//   loads of row r+1 are in flight while row r is reduced and its out row
//   streamed. bias/wsb (16 KB) stay L1-resident. No LDS, no barriers, no nt.

#define B_DIM 8192
#define IN_DIM 2048
#define OUT_DIM 2048
#define ROWS_PER_WAVE 4

typedef float f32x4 __attribute__((ext_vector_type(4)));

__device__ __forceinline__ float butterfly_reduce(float s) {
    #pragma unroll
    for (int off = 32; off; off >>= 1)
        s += __shfl_xor(s, off, 64);
    return s;   // result in all 64 lanes
}

__device__ __forceinline__ void load_row(f32x4 (&v)[8], const float* __restrict__ row,
                                         int lane) {
    const f32x4* r4 = reinterpret_cast<const f32x4*>(row);
    #pragma unroll
    for (int k = 0; k < 8; ++k)
        v[k] = r4[lane + (k << 6)];
}

__device__ __forceinline__ float reduce_row(const f32x4 (&v)[8]) {
    float s = 0.f;
    #pragma unroll
    for (int k = 0; k < 8; ++k)
        s += (v[k].x + v[k].y) + (v[k].z + v[k].w);
    return butterfly_reduce(s);
}

// 512 blocks x 256: one wave per w row.
__global__ __launch_bounds__(256) void wsb_kernel(const float* __restrict__ w,
                                                  const float* __restrict__ bias,
                                                  float* __restrict__ wsb) {
    const int wave = threadIdx.x >> 6;
    const int lane = threadIdx.x & 63;
    const int row  = (blockIdx.x << 2) + wave;           // 0 .. 2047
    f32x4 v[8];
    load_row(v, w + (size_t)row * IN_DIM, lane);
    float s = reduce_row(v);
    if (lane == 0)
        wsb[row] = s * bias[row];
}

// 512 blocks x 256: each wave owns 4 consecutive x rows, depth-2 pipelined.
__global__ __launch_bounds__(256) void fused_row_kernel(const float* __restrict__ x,
                                                        const float* __restrict__ bias,
                                                        const float* __restrict__ wsb,
                                                        f32x4* __restrict__ out4) {
    const int wave = threadIdx.x >> 6;
    const int lane = threadIdx.x & 63;
    const int row0 = ((blockIdx.x << 2) + wave) * ROWS_PER_WAVE;   // 0 .. 8191
    const f32x4* bias4 = reinterpret_cast<const f32x4*>(bias);
    const f32x4* wsb4  = reinterpret_cast<const f32x4*>(wsb);

    f32x4 cur[8], nxt[8];
    load_row(cur, x + (size_t)row0 * IN_DIM, lane);

    #pragma unroll
    for (int r = 0; r < ROWS_PER_WAVE; ++r) {
        if (r + 1 < ROWS_PER_WAVE)
            load_row(nxt, x + (size_t)(row0 + r + 1) * IN_DIM, lane);

        const float xs = reduce_row(cur);      // waits only on cur's 8 loads

        f32x4* orow = out4 + (size_t)(row0 + r) * (OUT_DIM / 4);
        #pragma unroll
        for (int k = 0; k < 8; ++k) {
            const int i = lane + (k << 6);
            const f32x4 bi = bias4[i];         // L1-resident (16 KB total)
            const f32x4 wv = wsb4[i];
            f32x4 o;
            o.x = fmaf(xs, bi.x, wv.x);
            o.y = fmaf(xs, bi.y, wv.y);
            o.z = fmaf(xs, bi.z, wv.z);
            o.w = fmaf(xs, bi.w, wv.w);
            orow[i] = o;
        }

        #pragma unroll
        for (int k = 0; k < 8; ++k)            // register rename, no copies emitted
            cur[k] = nxt[k];
    }
}

extern "C" void kernel_launch(void* const* d_in, const int* in_sizes, int n_in,
                              void* d_out, int out_size, void* d_ws, size_t ws_size,
                              hipStream_t stream) {
    const float* x    = (const float*)d_in[0];   // [8192, 2048]
    const float* w    = (const float*)d_in[1];   // [2048, 2048]
    const float* bias = (const float*)d_in[2];   // [2048]
    float* out = (float*)d_out;                  // [8192, 2048]
    float* wsb = (float*)d_ws;                   // 2048 floats

    wsb_kernel<<<OUT_DIM / 4, 256, 0, stream>>>(w, bias, wsb);
    fused_row_kernel<<<B_DIM / (4 * ROWS_PER_WAVE), 256, 0, stream>>>(x, bias, wsb,
                                                                     (f32x4*)out);
}

// Round 7
// 29.618 us; speedup vs baseline: 5.9508x; 1.0302x over previous
//
#include <hip/hip_runtime.h>

// out[b,o] = (rowsum(x)[b] + rowsum(w)[o]) * bias[o]
// B=8192, IN=2048, OUT=2048, all float32.
//
// Kernel A (pure-read): wave-per-row rowsums of x AND w.
//   xsum[b] = rowsum(x)[b]; wsb[o] = rowsum(w)[o] * bias[o].  (80 MiB read)
// Kernel B (pure-write, column-stationary): block owns full row width;
//   bias/wsb live in 16 VGPRs loaded ONCE; loop 4 rows, one broadcast xsum
//   load + coalesced stores. No per-element cache re-reads. (64 MiB write)

#define B_DIM 8192
#define IN_DIM 2048
#define OUT_DIM 2048

typedef float f32x4 __attribute__((ext_vector_type(4)));

__device__ __forceinline__ float butterfly_reduce(float s) {
    #pragma unroll
    for (int off = 32; off; off >>= 1)
        s += __shfl_xor(s, off, 64);
    return s;   // result in all 64 lanes
}

__device__ __forceinline__ float row_reduce(const float* __restrict__ row, int lane) {
    const f32x4* r4 = reinterpret_cast<const f32x4*>(row);
    f32x4 v[8];
    #pragma unroll
    for (int k = 0; k < 8; ++k)
        v[k] = r4[lane + (k << 6)];
    float s = 0.f;
    #pragma unroll
    for (int k = 0; k < 8; ++k)
        s += (v[k].x + v[k].y) + (v[k].z + v[k].w);
    return butterfly_reduce(s);
}

// 2560 blocks x 256 (4 waves): waves 0..8191 -> x rows, 8192..10239 -> w rows.
__global__ __launch_bounds__(256) void rowsum_kernel(const float* __restrict__ x,
                                                     const float* __restrict__ w,
                                                     const float* __restrict__ bias,
                                                     float* __restrict__ xsum,
                                                     float* __restrict__ wsb) {
    const int wid  = (blockIdx.x << 2) + (threadIdx.x >> 6);   // global wave id
    const int lane = threadIdx.x & 63;
    if (wid < B_DIM) {
        float s = row_reduce(x + (size_t)wid * IN_DIM, lane);
        if (lane == 0) xsum[wid] = s;
    } else {
        const int o = wid - B_DIM;                              // 0 .. 2047
        float s = row_reduce(w + (size_t)o * IN_DIM, lane);
        if (lane == 0) wsb[o] = s * bias[o];
    }
}

// 2048 blocks x 256: block covers all 2048 cols (2 f32x4/thread, regs),
// writes 4 consecutive rows.
__global__ __launch_bounds__(256) void write_kernel(const float* __restrict__ xsum,
                                                    const float* __restrict__ bias,
                                                    const float* __restrict__ wsb,
                                                    f32x4* __restrict__ out4) {
    const int tid  = threadIdx.x;
    const int rbase = blockIdx.x << 2;                   // 4 rows per block
    const f32x4* bias4 = reinterpret_cast<const f32x4*>(bias);
    const f32x4* wsb4  = reinterpret_cast<const f32x4*>(wsb);

    // column-stationary state: 16 VGPRs, loaded once
    const f32x4 b0 = bias4[tid];
    const f32x4 b1 = bias4[tid + 256];
    const f32x4 w0 = wsb4[tid];
    const f32x4 w1 = wsb4[tid + 256];

    // 4 row-scalars in one broadcast load
    const f32x4 xs4 = *reinterpret_cast<const f32x4*>(&xsum[rbase]);

    #pragma unroll
    for (int r = 0; r < 4; ++r) {
        const float xs = xs4[r];
        f32x4* orow = out4 + (size_t)(rbase + r) * (OUT_DIM / 4);
        f32x4 o0, o1;
        o0.x = fmaf(xs, b0.x, w0.x);
        o0.y = fmaf(xs, b0.y, w0.y);
        o0.z = fmaf(xs, b0.z, w0.z);
        o0.w = fmaf(xs, b0.w, w0.w);
        o1.x = fmaf(xs, b1.x, w1.x);
        o1.y = fmaf(xs, b1.y, w1.y);
        o1.z = fmaf(xs, b1.z, w1.z);
        o1.w = fmaf(xs, b1.w, w1.w);
        orow[tid]       = o0;
        orow[tid + 256] = o1;
    }
}

extern "C" void kernel_launch(void* const* d_in, const int* in_sizes, int n_in,
                              void* d_out, int out_size, void* d_ws, size_t ws_size,
                              hipStream_t stream) {
    const float* x    = (const float*)d_in[0];   // [8192, 2048]
    const float* w    = (const float*)d_in[1];   // [2048, 2048]
    const float* bias = (const float*)d_in[2];   // [2048]
    float* out  = (float*)d_out;                 // [8192, 2048]
    float* xsum = (float*)d_ws;                  // 8192 floats
    float* wsb  = xsum + B_DIM;                  // 2048 floats

    rowsum_kernel<<<(B_DIM + OUT_DIM) / 4, 256, 0, stream>>>(x, w, bias, xsum, wsb);
    write_kernel<<<B_DIM / 4, 256, 0, stream>>>(xsum, bias, wsb, (f32x4*)out);
}